// Round 1
// baseline (1763.901 us; speedup 1.0000x reference)
//
#include <hip/hip_runtime.h>
#include <math.h>

#define EDIM 4096
#define BS 32
#define NT 64       // final_kernel tile (unchanged)
#define NT2 128     // mm_stage: output columns per tile (= 2 cols/lane * 64 lanes)
#define NWAVES 4    // waves per block (in-block K split)
#define BLK 256

__device__ __forceinline__ float relu_f(float x) { return x > 0.f ? x : 0.f; }

// ---------------------------------------------------------------------------
// prep: A0 = relu(BN(image)) stored feature-major [E][32]; v = relu(fs_bn_b[E:2E]);
// flag = any(v != 0). Row-split across 4 thread groups -> 64 blocks (was 16),
// image row kept in registers between the stats pass and the write pass.
// ---------------------------------------------------------------------------
__global__ void __launch_bounds__(BLK) prep_kernel(
    const float* __restrict__ img, const float* __restrict__ bng,
    const float* __restrict__ bnb, float* __restrict__ act0,
    float* __restrict__ vvec, int* __restrict__ flag)
{
  __shared__ float ss[64][5], ss2[64][5];   // [c][rg], pad to 5 for banks
  __shared__ float ssc[64], ssh[64];
  const int tid = threadIdx.x;
  const int c  = tid & 63;        // column within block's 64-col slab
  const int rg = tid >> 6;        // row group (8 rows each)
  const int n  = blockIdx.x * 64 + c;

  float xv[8];
  float s = 0.f, s2 = 0.f;
#pragma unroll
  for (int u = 0; u < 8; ++u) {
    float x = img[(size_t)(rg * 8 + u) * EDIM + n];
    xv[u] = x; s += x; s2 += x * x;
  }
  ss[c][rg] = s; ss2[c][rg] = s2;
  __syncthreads();

  if (tid < 64) {
    float S  = ss[tid][0] + ss[tid][1] + ss[tid][2] + ss[tid][3];
    float S2 = ss2[tid][0] + ss2[tid][1] + ss2[tid][2] + ss2[tid][3];
    float mean = S * (1.f / BS);
    float var  = S2 * (1.f / BS) - mean * mean;
    int nn = blockIdx.x * 64 + tid;
    float sc = bng[nn] * rsqrtf(var + 1e-5f);
    ssc[tid] = sc;
    ssh[tid] = bnb[nn] - mean * sc;
    // text half of BN(concat) is exactly fs_bn_b[E:2E] (constant rows -> x==mu)
    float vv = relu_f(bnb[EDIM + nn]);
    vvec[nn] = vv;
    if (vv != 0.f) atomicOr(flag, 1);
  }
  __syncthreads();

  const float sc = ssc[c], sh = ssh[c];
#pragma unroll
  for (int u = 0; u < 8; ++u)
    act0[(size_t)n * BS + rg * 8 + u] = relu_f(xv[u] * sc + sh);
}

// ---------------------------------------------------------------------------
// One GEMM stage: OUT[r][n] = sum_k Ain[k][r] * W[k][n].
// Each lane owns 2 consecutive columns (float2 W loads = 512B/wave-instr).
// Block = 4 waves splitting K 4-way over a 128-col tile; grid adds KG=2^kgShift
// K-groups per tile (512 blocks/stage -> 2 blocks/CU), combined with fp32
// atomics; last K-group block per tile applies the epilogue:
//   mode 0: +bias (fs; optional lower-half text contribution) -> dst[n][r]
//   mode 1: +bias -> batch-BN -> relu -> dst[n][r]
//   mode 2: +bias -> sigmoid -> dst row-major [r][EDIM]
//   mode 3: +bias + residual[n][r] -> dst[n][r]
// ---------------------------------------------------------------------------
__global__ void __launch_bounds__(BLK, 2) mm_stage(
    const float* __restrict__ W, const float* __restrict__ Ain,
    const float* __restrict__ bias,
    const float* __restrict__ bng, const float* __restrict__ bnb,
    const float* __restrict__ res,
    const float* __restrict__ Wlow, const float* __restrict__ vvec,
    const int* __restrict__ flag,
    float* __restrict__ acc, int* __restrict__ counter,
    float* __restrict__ dst,
    int K, int N, int kgShift, int mode)
{
  const int tid  = threadIdx.x;
  const int bx   = blockIdx.x;
  const int KG   = 1 << kgShift;
  const int tile = bx >> kgShift;
  const int ks   = bx & (KG - 1);
  const int wv   = __builtin_amdgcn_readfirstlane(tid >> 6);
  const int lane = tid & 63;
  const int n0   = tile * NT2 + lane * 2;
  const int kchunk = K >> (kgShift + 2);     // K / (KG*NWAVES)
  const int k0     = (ks * NWAVES + wv) * kchunk;

  float r0[BS], r1[BS];
#pragma unroll
  for (int r = 0; r < BS; ++r) { r0[r] = 0.f; r1[r] = 0.f; }

  const float* __restrict__ wp = W + (size_t)k0 * N + n0;
  const float* __restrict__ ap = Ain + (size_t)k0 * BS;

  // unroll 4: 4 independent 512B W loads in flight per wave; with 8 waves/CU
  // that's ~16KB outstanding > the ~9.2KB (10.2 B/cyc * 900cy) latency product.
#pragma unroll 4
  for (int k = 0; k < kchunk; ++k) {
    const float2 w2 = *(const float2*)(wp + (size_t)k * N);
    const float* __restrict__ arow = ap + (size_t)k * BS;   // wave-uniform
#pragma unroll
    for (int q = 0; q < 8; ++q) {
      const float4 a4 = *(const float4*)(arow + (q << 2));
      const int b = q << 2;
      r0[b+0] = fmaf(a4.x, w2.x, r0[b+0]);  r1[b+0] = fmaf(a4.x, w2.y, r1[b+0]);
      r0[b+1] = fmaf(a4.y, w2.x, r0[b+1]);  r1[b+1] = fmaf(a4.y, w2.y, r1[b+1]);
      r0[b+2] = fmaf(a4.z, w2.x, r0[b+2]);  r1[b+2] = fmaf(a4.z, w2.y, r1[b+2]);
      r0[b+3] = fmaf(a4.w, w2.x, r0[b+3]);  r1[b+3] = fmaf(a4.w, w2.y, r1[b+3]);
    }
  }

  // fs lower half: only if relu(fs_bn_b[E:]) has any nonzero (uniform branch;
  // zero for the given inputs -> skipped, no 64MB read).
  if (Wlow != nullptr) {
    if (*flag) {
      float c0 = 0.f, c1 = 0.f;
      const float* __restrict__ wl = Wlow + (size_t)k0 * N + n0;
#pragma unroll 4
      for (int k = 0; k < kchunk; ++k) {
        const float2 w2 = *(const float2*)(wl + (size_t)k * N);
        const float vvk = vvec[k0 + k];
        c0 = fmaf(vvk, w2.x, c0);
        c1 = fmaf(vvk, w2.y, c1);
      }
#pragma unroll
      for (int r = 0; r < BS; ++r) { r0[r] += c0; r1[r] += c1; }
    }
  }

  // intra-block reduce across the 4 waves.
  // Row stride BS+4=36 floats = 144B: keeps float4 (b128) accesses 16B-aligned
  // and limits bank aliasing to ~2x (vs 8x unpadded).
  __shared__ float sred[NWAVES][NT2][BS + 4];
#pragma unroll
  for (int r = 0; r < BS; r += 4) {
    *(float4*)&sred[wv][lane * 2 + 0][r] = make_float4(r0[r], r0[r+1], r0[r+2], r0[r+3]);
    *(float4*)&sred[wv][lane * 2 + 1][r] = make_float4(r1[r], r1[r+1], r1[r+2], r1[r+3]);
  }
  __syncthreads();

  const int c  = tid >> 1;          // column within tile (0..127)
  const int rb = (tid & 1) * 16;    // row half (0,16)
  float tot[16];
#pragma unroll
  for (int u = 0; u < 16; u += 4) {
    float4 t0 = *(const float4*)&sred[0][c][rb + u];
    float4 t1 = *(const float4*)&sred[1][c][rb + u];
    float4 t2 = *(const float4*)&sred[2][c][rb + u];
    float4 t3 = *(const float4*)&sred[3][c][rb + u];
    tot[u+0] = t0.x + t1.x + t2.x + t3.x;
    tot[u+1] = t0.y + t1.y + t2.y + t3.y;
    tot[u+2] = t0.z + t1.z + t2.z + t3.z;
    tot[u+3] = t0.w + t1.w + t2.w + t3.w;
  }

  const int col = tile * NT2 + c;
  float* ga = acc + (size_t)col * BS + rb;
#pragma unroll
  for (int u = 0; u < 16; ++u) atomicAdd(ga + u, tot[u]);

  __threadfence();
  __syncthreads();
  __shared__ int s_last;
  if (tid == 0) {
    int old = atomicAdd(counter + tile, 1);
    s_last = (old == KG - 1) ? 1 : 0;
  }
  __syncthreads();
  if (!s_last) return;

  // finishing block: re-read completed sums coherently (bypass L1)
  float val[16];
#pragma unroll
  for (int u = 0; u < 16; ++u)
    val[u] = __hip_atomic_load(ga + u, __ATOMIC_RELAXED, __HIP_MEMORY_SCOPE_AGENT);

  const float bb = bias[col];
#pragma unroll
  for (int u = 0; u < 16; ++u) val[u] += bb;

  if (mode == 1) {
    __shared__ float sps[NT2][2], sps2[NT2][2], ssc[NT2], ssh[NT2];
    float p = 0.f, p2 = 0.f;
#pragma unroll
    for (int u = 0; u < 16; ++u) { p += val[u]; p2 += val[u] * val[u]; }
    sps[c][tid & 1] = p; sps2[c][tid & 1] = p2;
    __syncthreads();
    if (tid < NT2) {
      float s  = sps[tid][0] + sps[tid][1];
      float s2 = sps2[tid][0] + sps2[tid][1];
      float mean = s * (1.f / BS);
      float var  = s2 * (1.f / BS) - mean * mean;
      float sc = bng[tile * NT2 + tid] * rsqrtf(var + 1e-5f);
      ssc[tid] = sc;
      ssh[tid] = bnb[tile * NT2 + tid] - mean * sc;
    }
    __syncthreads();
    float sc = ssc[c], sh = ssh[c];
    float* dp = dst + (size_t)col * BS + rb;
#pragma unroll
    for (int u = 0; u < 16; ++u) dp[u] = relu_f(val[u] * sc + sh);
  } else if (mode == 2) {
#pragma unroll
    for (int u = 0; u < 16; ++u) {
      float g = 1.f / (1.f + __expf(-val[u]));
      dst[(size_t)(rb + u) * EDIM + col] = g;   // row-major for final kernel
    }
  } else if (mode == 3) {
    const float* rp = res + (size_t)col * BS + rb;
    float* dp = dst + (size_t)col * BS + rb;
#pragma unroll
    for (int u = 0; u < 16; ++u) dp[u] = val[u] + rp[u];
  } else {
    float* dp = dst + (size_t)col * BS + rb;
#pragma unroll
    for (int u = 0; u < 16; ++u) dp[u] = val[u];
  }
}

// ---------------------------------------------------------------------------
// final: out[j][r][e] = img[r][e]*g[r][e] + ff[r][e]*(1-g[r][e]), identical for
// all j -> compute once, write 8 j-copies per block (4 j-groups x 64 e-tiles).
// ---------------------------------------------------------------------------
__global__ void __launch_bounds__(BLK) final_kernel(
    const float* __restrict__ img, const float* __restrict__ grm,
    const float* __restrict__ fft, float* __restrict__ out)
{
  __shared__ float sff[BS][NT];   // transposed stage: read [e][r] -> serve [r][e]
  const int tid  = threadIdx.x;
  const int tile = blockIdx.x & 63;
  const int jg   = blockIdx.x >> 6;
  const int c  = tid >> 2;
  const int rb = (tid & 3) * 8;
  const float* src = fft + (size_t)(tile * NT + c) * BS + rb;
#pragma unroll
  for (int u = 0; u < 8; ++u) sff[rb + u][c] = src[u];
  __syncthreads();

  const int le = tid & 63, rg = tid >> 6;
  const int e  = tile * NT + le;
#pragma unroll
  for (int rr = 0; rr < 8; ++rr) {
    int r = rr * 4 + rg;
    float gv = grm[(size_t)r * EDIM + e];
    float iv = img[(size_t)r * EDIM + e];
    float o  = iv * gv + sff[r][le] * (1.f - gv);
#pragma unroll
    for (int jj = 0; jj < 8; ++jj) {
      int j = jg * 8 + jj;
      out[((size_t)(j * BS + r)) * EDIM + e] = o;
    }
  }
}

// ---------------------------------------------------------------------------
extern "C" void kernel_launch(void* const* d_in, const int* in_sizes, int n_in,
                              void* d_out, int out_size, void* d_ws, size_t ws_size,
                              hipStream_t stream)
{
  const float* img    = (const float*)d_in[0];
  // d_in[1] text_features: provably unused (BN of constant batch rows)
  const float* fs_bng = (const float*)d_in[2];
  const float* fs_bnb = (const float*)d_in[3];
  const float* fs_w   = (const float*)d_in[4];
  const float* fs_b   = (const float*)d_in[5];
  const float* gt_w1  = (const float*)d_in[6];
  const float* gt_b1  = (const float*)d_in[7];
  const float* gt_bng = (const float*)d_in[8];
  const float* gt_bnb = (const float*)d_in[9];
  const float* gt_w2  = (const float*)d_in[10];
  const float* gt_b2  = (const float*)d_in[11];
  const float* ee_w1  = (const float*)d_in[12];
  const float* ee_b1  = (const float*)d_in[13];
  const float* ee_bng = (const float*)d_in[14];
  const float* ee_bnb = (const float*)d_in[15];
  const float* ee_w2  = (const float*)d_in[16];
  const float* ee_b2  = (const float*)d_in[17];
  float* out = (float*)d_out;

  float* w = (float*)d_ws;
  size_t o = 0;
  float* acc_fs = w + o; o += (size_t)EDIM * BS;
  float* acc_g1 = w + o; o += (size_t)EDIM * BS;
  float* acc_g2 = w + o; o += (size_t)EDIM * BS;
  float* acc_ea[3]; for (int i = 0; i < 3; ++i) { acc_ea[i] = w + o; o += (size_t)(EDIM/2) * BS; }
  float* acc_eb[3]; for (int i = 0; i < 3; ++i) { acc_eb[i] = w + o; o += (size_t)EDIM * BS; }
  int* counters = (int*)(w + o); o += 1024;   // 9 stages x <=32 tiles + flag, zeroed
  int* flag = counters + 960;
  size_t zero_bytes = o * sizeof(float);
  float* act0 = w + o; o += (size_t)EDIM * BS;
  float* vvec = w + o; o += EDIM;
  float* fbuf = w + o; o += (size_t)EDIM * BS;
  float* hgb  = w + o; o += (size_t)EDIM * BS;
  float* gbuf = w + o; o += (size_t)EDIM * BS;
  float* he[3];  for (int i = 0; i < 3; ++i) { he[i]  = w + o; o += (size_t)(EDIM/2) * BS; }
  float* ffb[3]; for (int i = 0; i < 3; ++i) { ffb[i] = w + o; o += (size_t)EDIM * BS; }

  hipMemsetAsync(d_ws, 0, zero_bytes, stream);

  prep_kernel<<<EDIM / 64, BLK, 0, stream>>>(img, fs_bng, fs_bnb, act0, vvec, flag);

  // fs: f = A0 @ fs_w[:E] + fs_b (+ optional text-bias term via Wlow)
  // N=4096: 32 tiles x KG=16 -> 512 blocks (2 blocks/CU)
  mm_stage<<<(EDIM / NT2) * 16, BLK, 0, stream>>>(
      fs_w, act0, fs_b, nullptr, nullptr, nullptr,
      fs_w + (size_t)EDIM * EDIM, vvec, flag,
      acc_fs, counters + 0, fbuf, EDIM, EDIM, 4, 0);

  // gating
  mm_stage<<<(EDIM / NT2) * 16, BLK, 0, stream>>>(
      gt_w1, fbuf, gt_b1, gt_bng, gt_bnb, nullptr, nullptr, nullptr, nullptr,
      acc_g1, counters + 64, hgb, EDIM, EDIM, 4, 1);
  mm_stage<<<(EDIM / NT2) * 16, BLK, 0, stream>>>(
      gt_w2, hgb, gt_b2, nullptr, nullptr, nullptr, nullptr, nullptr, nullptr,
      acc_g2, counters + 128, gbuf, EDIM, EDIM, 4, 2);

  // 3 error-encoding residual blocks
  const float* ffin = fbuf;
  for (int i = 0; i < 3; ++i) {
    // ee_a: N=2048: 16 tiles x KG=32 -> 512 blocks
    mm_stage<<<((EDIM / 2) / NT2) * 32, BLK, 0, stream>>>(
        ee_w1 + (size_t)i * EDIM * (EDIM / 2), ffin,
        ee_b1 + (size_t)i * (EDIM / 2), ee_bng + (size_t)i * (EDIM / 2),
        ee_bnb + (size_t)i * (EDIM / 2),
        nullptr, nullptr, nullptr, nullptr,
        acc_ea[i], counters + 192 + i * 128, he[i], EDIM, EDIM / 2, 5, 1);
    // ee_b: K=2048, N=4096: 32 tiles x KG=16 -> 512 blocks
    mm_stage<<<(EDIM / NT2) * 16, BLK, 0, stream>>>(
        ee_w2 + (size_t)i * (EDIM / 2) * EDIM, he[i],
        ee_b2 + (size_t)i * EDIM, nullptr, nullptr, ffin,
        nullptr, nullptr, nullptr,
        acc_eb[i], counters + 256 + i * 128, ffb[i], EDIM / 2, EDIM, 4, 3);
    ffin = ffb[i];
  }

  final_kernel<<<64 * 4, BLK, 0, stream>>>(img, gbuf, ffin, out);
}